// Round 11
// baseline (675.364 us; speedup 1.0000x reference)
//
#include <hip/hip_runtime.h>
#include <hip/hip_bf16.h>

// QRNN: T=512, B=64, IN=512, H=1024, OUT=512. fp32 in/out.
// R13 (resubmit; R10-slot bench lost to GPUAcquisitionTimeout -- no data).
// Post-mortem of R8-R12: four GEMM schedule variants all pinned at
// 121-124us -> K-step micro-schedule is NOT the lever at 1 block/CU; GEMM is
// at its structure-class ceiling (~832 TF). This round: revert GEMM to the
// measured-best R10 variant (121.1us, VGPR 92) and attack the ~170us of
// scan-latency + launch gaps: (1) scan_p3 lookback was a serial dependent-
// load chain (<=31 iters x ~200cy L2 latency); batch 8 (A,B) pairs into regs
// (loads pipeline), fold in the SAME order -> bitwise identical. (2) drop
// the dead cstart slot from the CW budget -> CW=1024/nch=1 fits if ws
// permits (6 fewer launches; falls back to 512 harmlessly).
// Retained: 256x256 tile, BK=32 4-slot ring, 2-phase K-loop w/ lgkm(0)+
// setprio, counted vmcnt(8/4/0), XCD-chunked bijective remap, 0-conflict
// XOR swizzle, fast exp2/rcp activations, row-inner epilogue, 4-wide scans,
// p2-in-p3 fold, bf16 g, x_bf aliased into h1, RNE f2bf.

#define QT 512
#define QB 64
#define QIN 512
#define QH 1024
#define QOUT 512
#define QM (QT * QB)
#define SEG 32
#define SL (QT / SEG)  // 16

typedef unsigned short ushort_t;
typedef __attribute__((ext_vector_type(8))) short bf16x8;
typedef __attribute__((ext_vector_type(4))) float f32x4;

__device__ __forceinline__ float blo(unsigned int u) {
    union { unsigned int i; float f; } v;
    v.i = u << 16;
    return v.f;
}

__device__ __forceinline__ float bhi(unsigned int u) {
    union { unsigned int i; float f; } v;
    v.i = u & 0xffff0000u;
    return v.f;
}

__device__ __forceinline__ ushort_t f2bf(float f) {
    union { float f; unsigned int i; } v;
    v.f = f;
    unsigned int r = v.i + 0x7fffu + ((v.i >> 16) & 1u);  // RNE
    return (ushort_t)(r >> 16);
}

__device__ __forceinline__ void glds16(const ushort_t* g, ushort_t* l) {
    __builtin_amdgcn_global_load_lds(
        (const __attribute__((address_space(1))) void*)g,
        (__attribute__((address_space(3))) void*)l, 16, 0, 0);
}

// --------------------------- pre-pass kernels ------------------------------
__global__ __launch_bounds__(256) void cvt_bf16(const float* __restrict__ src,
                                                ushort_t* __restrict__ dst) {
    const int i = blockIdx.x * 256 + threadIdx.x;
    float4 v = ((const float4*)src)[i];
    ushort4 o;
    o.x = f2bf(v.x); o.y = f2bf(v.y); o.z = f2bf(v.z); o.w = f2bf(v.w);
    ((ushort4*)dst)[i] = o;
}

// W (K x N fp32) -> WT (N x K bf16)
__global__ __launch_bounds__(256) void transpose_cvt(
    const float* __restrict__ W, ushort_t* __restrict__ WT, int K, int N) {
    __shared__ float t[32][33];
    const int tx = threadIdx.x & 31, ty = threadIdx.x >> 5;
    const int n0 = blockIdx.x * 32, k0 = blockIdx.y * 32;
#pragma unroll
    for (int i = 0; i < 4; ++i)
        t[ty + 8 * i][tx] = W[(size_t)(k0 + ty + 8 * i) * N + n0 + tx];
    __syncthreads();
#pragma unroll
    for (int i = 0; i < 4; ++i)
        WT[(size_t)(n0 + ty + 8 * i) * K + k0 + tx] = f2bf(t[tx][ty + 8 * i]);
}

// ------------------------------ MFMA GEMM ----------------------------------
// C = A(M x K bf16 rm) @ BT(N x K bf16 rm)^T. 512 thr = 8 waves (2M x 4N),
// tile 256x256, per-wave 128x64. BK=32, 4-slot LDS ring, 2 phases/K-step.
// MODE 0: bf16 g-chunk out, tanh(gate0)/sigmoid(gates1,2). MODE 1: fp32 FC.
// (R10 variant -- measured best: 121.1us L1, MfmaUtil 35.8%, VGPR 92.)
template <int MODE, int K>
__global__ __launch_bounds__(512, 2) void gemm256(
    const ushort_t* __restrict__ A, const ushort_t* __restrict__ BT,
    const float* __restrict__ bias, void* __restrict__ out,
    int c0, int CW) {
    constexpr int NT = K / 32;
    __shared__ ushort_t As[4 * 8192];  // 4 slots x (256 rows x 32 k) = 64 KiB
    __shared__ ushort_t Bs[4 * 8192];  // 64 KiB

    const int tid = threadIdx.x;
    const int lane = tid & 63;
    const int w = tid >> 6;
    const int wr = w >> 2, wc = w & 3;

    // T1: XCD-chunked bijective remap (nwg % 8 == 0 always), M-major within.
    const int gx = gridDim.x;
    const int nwg = gx * gridDim.y;
    int flat = blockIdx.y * gx + blockIdx.x;
    flat = (flat & 7) * (nwg >> 3) + (flat >> 3);
    const int by = flat / gx;
    const int bx = flat - by * gx;
    const int m0 = by * 256;

    int nW, nOut, outstride, gate = 0;
    if (MODE == 0) {
        const int per = CW >> 8;
        gate = bx / per;
        const int nloc = (bx - gate * per) * 256;
        nW = gate * QH + c0 + nloc;
        nOut = gate * CW + nloc;
        outstride = 3 * CW;
    } else {
        nW = bx * 256;
        nOut = nW;
        outstride = QOUT;
    }

    // Staging: 1024 16B-chunks per array per tile; thread covers 2 (A) + 2 (B).
    // LDS linear; global source pre-swizzled: gsrc = glds ^ ((row>>1)&3).
    size_t aoff[2], boff[2];
    int ldso[2];
#pragma unroll
    for (int j = 0; j < 2; ++j) {
        const int c = w * 128 + j * 64 + lane;  // chunk id 0..1023
        const int r = c >> 2;
        const int gs = (c & 3) ^ ((r >> 1) & 3);
        aoff[j] = (size_t)(m0 + r) * K + gs * 8;
        boff[j] = (size_t)(nW + r) * K + gs * 8;
        ldso[j] = w * 1024 + j * 512;  // wave-uniform elems (HW adds lane*16B)
    }

    const int fl = lane & 15, fq = lane >> 4;
    const int laneoff = fl * 32 + ((fq ^ ((fl >> 1) & 3)) << 3);

    f32x4 acc[8][4];
#pragma unroll
    for (int i = 0; i < 8; ++i)
#pragma unroll
        for (int j = 0; j < 4; ++j) acc[i][j] = {0.f, 0.f, 0.f, 0.f};

    // Prologue: stage tiles 0,1,2 -> slots 0,1,2; wait tile0 (8 newest fly).
#pragma unroll
    for (int t = 0; t < 3; ++t) {
        const int slot = t * 8192;
#pragma unroll
        for (int j = 0; j < 2; ++j)
            glds16(A + aoff[j] + t * 32, &As[slot + ldso[j]]);
#pragma unroll
        for (int j = 0; j < 2; ++j)
            glds16(BT + boff[j] + t * 32, &Bs[slot + ldso[j]]);
    }
    asm volatile("s_waitcnt vmcnt(8)" ::: "memory");
    __builtin_amdgcn_s_barrier();

    for (int kt = 0; kt < NT; ++kt) {
        const int slot = (kt & 3) * 8192;
        const int sa = slot + wr * 4096 + laneoff;
        const int sb = slot + wc * 2048 + laneoff;
        const bool pf = (kt + 3 < NT);
        const int pslot = ((kt + 3) & 3) * 8192;
        const size_t kb = (size_t)(kt + 3) * 32;

        bf16x8 a0[4], a1[4], bv[4];
        // ---------------- phase 0: i=0..3, stage A-pair of kt+3 ----------
#pragma unroll
        for (int i = 0; i < 4; ++i) a0[i] = *(const bf16x8*)&As[sa + i * 512];
#pragma unroll
        for (int j = 0; j < 4; ++j) bv[j] = *(const bf16x8*)&Bs[sb + j * 512];
        if (pf) {
#pragma unroll
            for (int j = 0; j < 2; ++j)
                glds16(A + aoff[j] + kb, &As[pslot + ldso[j]]);
        }
        __builtin_amdgcn_sched_barrier(0);
        __builtin_amdgcn_s_barrier();
        asm volatile("s_waitcnt lgkmcnt(0)" ::: "memory");
        __builtin_amdgcn_sched_barrier(0);
        __builtin_amdgcn_s_setprio(1);
#pragma unroll
        for (int i = 0; i < 4; ++i)
#pragma unroll
            for (int j = 0; j < 4; ++j)
                acc[i][j] = __builtin_amdgcn_mfma_f32_16x16x32_bf16(
                    a0[i], bv[j], acc[i][j], 0, 0, 0);
        __builtin_amdgcn_s_setprio(0);
        __builtin_amdgcn_sched_barrier(0);
        __builtin_amdgcn_s_barrier();
        // ---------------- phase 1: i=4..7, stage B-pair of kt+3 ----------
#pragma unroll
        for (int i = 0; i < 4; ++i)
            a1[i] = *(const bf16x8*)&As[sa + (4 + i) * 512];
        if (pf) {
#pragma unroll
            for (int j = 0; j < 2; ++j)
                glds16(BT + boff[j] + kb, &Bs[pslot + ldso[j]]);
        }
        __builtin_amdgcn_sched_barrier(0);
        __builtin_amdgcn_s_barrier();
        asm volatile("s_waitcnt lgkmcnt(0)" ::: "memory");
        __builtin_amdgcn_sched_barrier(0);
        __builtin_amdgcn_s_setprio(1);
#pragma unroll
        for (int i = 0; i < 4; ++i)
#pragma unroll
            for (int j = 0; j < 4; ++j)
                acc[4 + i][j] = __builtin_amdgcn_mfma_f32_16x16x32_bf16(
                    a1[i], bv[j], acc[4 + i][j], 0, 0, 0);
        __builtin_amdgcn_s_setprio(0);
        // End-of-step vmcnt: tiles <= kt+1 retired; in-flight = stages of
        // kt+2, kt+3 (4 loads each).
        if (kt < NT - 3)
            asm volatile("s_waitcnt vmcnt(8)" ::: "memory");
        else if (kt == NT - 3)
            asm volatile("s_waitcnt vmcnt(4)" ::: "memory");
        else if (kt == NT - 2)
            asm volatile("s_waitcnt vmcnt(0)" ::: "memory");
        __builtin_amdgcn_sched_barrier(0);
        if (kt < NT - 1) __builtin_amdgcn_s_barrier();
    }

    // Fast activation constants (wave-uniform): v = a*rcp(1+exp2(k*v)) + d.
    const float ak = (gate == 0) ? 2.8853900817779268f : -1.4426950408889634f;
    const float aa = (gate == 0) ? -2.f : 1.f;
    const float ad = (gate == 0) ? 1.f : 0.f;

    // Epilogue. C/D: col = lane&15, row = (lane>>4)*4 + reg. Row-inner j-loop
    // so the 4 32B sector-stores of each 128B line issue back-to-back.
    float bvv[4];
#pragma unroll
    for (int j = 0; j < 4; ++j) bvv[j] = bias[nW + wc * 64 + j * 16 + fl];
#pragma unroll
    for (int i = 0; i < 8; ++i) {
#pragma unroll
        for (int r = 0; r < 4; ++r) {
            const int row = m0 + wr * 128 + i * 16 + fq * 4 + r;
#pragma unroll
            for (int j = 0; j < 4; ++j) {
                const int col = nOut + wc * 64 + j * 16 + fl;
                float v = acc[i][j][r] + bvv[j];
                if (MODE == 0) {
                    v = aa * __builtin_amdgcn_rcpf(
                                 1.f + __builtin_amdgcn_exp2f(ak * v)) +
                        ad;
                    ((ushort_t*)out)[(size_t)row * outstride + col] = f2bf(v);
                } else {
                    ((float*)out)[(size_t)row * outstride + col] = v;
                }
            }
        }
    }
}

// ----------------------- segmented fo-scan (2 passes) ----------------------
// g: (T, B, 3, CW) bf16 activated z,f,o. c = f*c + (1-f)*z as (A,B) pairs.
// 4-wide: each thread owns 4 consecutive hh.

// Pass 1: per-(seg,b,hh4) summary. idx4 covers hh = 4*(idx4 % (CW/4)).
__global__ __launch_bounds__(256) void scan_p1(const ushort_t* __restrict__ g,
                                               float* __restrict__ Aseg,
                                               float* __restrict__ Bseg,
                                               int CW) {
    const int idx4 = blockIdx.x * 256 + threadIdx.x;
    const int cw4 = CW >> 2;
    const int hh = (idx4 % cw4) << 2;
    const int sb = idx4 / cw4;
    const int b = sb % QB;
    const int s = sb / QB;
    const ushort_t* gp = g + ((size_t)(s * SL * QB + b) * 3) * CW + hh;
    const size_t grow = (size_t)QB * 3 * CW;
    uint2 zu[SL], fu[SL];
#pragma unroll
    for (int t = 0; t < SL; ++t) {
        zu[t] = *(const uint2*)gp;
        fu[t] = *(const uint2*)(gp + CW);
        gp += grow;
    }
    float4 A = {1.f, 1.f, 1.f, 1.f}, Bc = {0.f, 0.f, 0.f, 0.f};
#pragma unroll
    for (int t = 0; t < SL; ++t) {
        const float f0 = blo(fu[t].x), f1 = bhi(fu[t].x);
        const float f2 = blo(fu[t].y), f3 = bhi(fu[t].y);
        Bc.x = f0 * Bc.x + (1.f - f0) * blo(zu[t].x);
        Bc.y = f1 * Bc.y + (1.f - f1) * bhi(zu[t].x);
        Bc.z = f2 * Bc.z + (1.f - f2) * blo(zu[t].y);
        Bc.w = f3 * Bc.w + (1.f - f3) * bhi(zu[t].y);
        A.x *= f0; A.y *= f1; A.z *= f2; A.w *= f3;
    }
    const size_t oidx = (size_t)sb * CW + hh;
    *(float4*)&Aseg[oidx] = A;
    *(float4*)&Bseg[oidx] = Bc;
}

// Pass 2 (p2+p3 fused): inline-scan preceding segment summaries for cstart
// (R13: batched 8-wide lookback -- loads pipeline instead of a serial
// dependent-load chain; fold order unchanged -> bitwise identical), then
// recompute interior states, write h (bf16, 4-wide).
__global__ __launch_bounds__(256) void scan_p3(const ushort_t* __restrict__ g,
                                               const float* __restrict__ Aseg,
                                               const float* __restrict__ Bseg,
                                               ushort_t* __restrict__ h,
                                               int c0, int CW) {
    const int idx4 = blockIdx.x * 256 + threadIdx.x;
    const int cw4 = CW >> 2;
    const int hh = (idx4 % cw4) << 2;
    const int sb = idx4 / cw4;
    const int b = sb % QB;
    const int s = sb / QB;
    const ushort_t* gp = g + ((size_t)(s * SL * QB + b) * 3) * CW + hh;
    ushort_t* hp = h + (size_t)(s * SL * QB + b) * QH + c0 + hh;
    const size_t grow = (size_t)QB * 3 * CW;
    const size_t hrow = (size_t)QB * QH;
    uint2 zu[SL], fu[SL], ou[SL];
#pragma unroll
    for (int t = 0; t < SL; ++t) {
        zu[t] = *(const uint2*)gp;
        fu[t] = *(const uint2*)(gp + CW);
        ou[t] = *(const uint2*)(gp + 2 * CW);
        gp += grow;
    }
    // Inline p2: c = fold over segments s' < s, batched 8 at a time.
    float4 c = {0.f, 0.f, 0.f, 0.f};
    const size_t stride = (size_t)QB * CW;
    const size_t colo = (size_t)b * CW + hh;
    int sp = 0;
    while (sp + 8 <= s) {
        float4 Av[8], Bv[8];
#pragma unroll
        for (int q = 0; q < 8; ++q) {
            const size_t o = (size_t)(sp + q) * stride + colo;
            Av[q] = *(const float4*)&Aseg[o];
            Bv[q] = *(const float4*)&Bseg[o];
        }
#pragma unroll
        for (int q = 0; q < 8; ++q) {
            c.x = Av[q].x * c.x + Bv[q].x;
            c.y = Av[q].y * c.y + Bv[q].y;
            c.z = Av[q].z * c.z + Bv[q].z;
            c.w = Av[q].w * c.w + Bv[q].w;
        }
        sp += 8;
    }
    if (sp < s) {
        float4 Av[8], Bv[8];
#pragma unroll
        for (int q = 0; q < 8; ++q) {
            const int si = (sp + q < SEG) ? sp + q : SEG - 1;  // clamp, in-bounds
            const size_t o = (size_t)si * stride + colo;
            Av[q] = *(const float4*)&Aseg[o];
            Bv[q] = *(const float4*)&Bseg[o];
        }
#pragma unroll
        for (int q = 0; q < 8; ++q) {
            if (sp + q < s) {
                c.x = Av[q].x * c.x + Bv[q].x;
                c.y = Av[q].y * c.y + Bv[q].y;
                c.z = Av[q].z * c.z + Bv[q].z;
                c.w = Av[q].w * c.w + Bv[q].w;
            }
        }
    }
#pragma unroll
    for (int t = 0; t < SL; ++t) {
        const float f0 = blo(fu[t].x), f1 = bhi(fu[t].x);
        const float f2 = blo(fu[t].y), f3 = bhi(fu[t].y);
        c.x = f0 * c.x + (1.f - f0) * blo(zu[t].x);
        c.y = f1 * c.y + (1.f - f1) * bhi(zu[t].x);
        c.z = f2 * c.z + (1.f - f2) * blo(zu[t].y);
        c.w = f3 * c.w + (1.f - f3) * bhi(zu[t].y);
        ushort4 hv;
        hv.x = f2bf(blo(ou[t].x) * c.x);
        hv.y = f2bf(bhi(ou[t].x) * c.y);
        hv.z = f2bf(blo(ou[t].y) * c.z);
        hv.w = f2bf(bhi(ou[t].y) * c.w);
        *(ushort4*)hp = hv;
        hp += hrow;
    }
}

extern "C" void kernel_launch(void* const* d_in, const int* in_sizes, int n_in,
                              void* d_out, int out_size, void* d_ws,
                              size_t ws_size, hipStream_t stream) {
    const float* x   = (const float*)d_in[0];
    const float* W0  = (const float*)d_in[1];
    const float* b0  = (const float*)d_in[2];
    const float* W1  = (const float*)d_in[3];
    const float* b1  = (const float*)d_in[4];
    const float* Wfc = (const float*)d_in[5];
    const float* bfc = (const float*)d_in[6];
    float* out = (float*)d_out;

    char* p = (char*)d_ws;
    ushort_t* h0   = (ushort_t*)p;  p += (size_t)QM * QH * 2;
    ushort_t* h1   = (ushort_t*)p;  // x_bf aliases h1 (dead before h1 write)
    ushort_t* x_bf = (ushort_t*)p;  p += (size_t)QM * QH * 2;
    ushort_t* W0T  = (ushort_t*)p;  p += (size_t)3 * QH * QIN * 2;
    ushort_t* W1T  = (ushort_t*)p;  p += (size_t)3 * QH * QH * 2;
    ushort_t* WfcT = (ushort_t*)p;  p += (size_t)QOUT * QH * 2;
    const size_t base = (size_t)(p - (char*)d_ws);

    // Largest CW (>=256) fitting ws. R13: budget only needs Aseg+Bseg now
    // (cstart slot dropped) -> CW=1024/nch=1 if ws permits (6 fewer launches).
    int CW = QH;
    while (CW > 256 &&
           base + 2 * (size_t)QB * CW * SEG * 4 + (size_t)QM * 3 * CW * 2 >
               ws_size)
        CW >>= 1;
    const int nch = QH / CW;

    float* Aseg   = (float*)p;  p += (size_t)QB * CW * SEG * 4;
    float* Bseg   = (float*)p;  p += (size_t)QB * CW * SEG * 4;
    ushort_t* g   = (ushort_t*)p;

    dim3 blk(256);
    dim3 blk5(512);

    cvt_bf16<<<dim3(QM * QIN / 1024), blk, 0, stream>>>(x, x_bf);
    transpose_cvt<<<dim3(3 * QH / 32, QIN / 32), blk, 0, stream>>>(
        W0, W0T, QIN, 3 * QH);
    transpose_cvt<<<dim3(3 * QH / 32, QH / 32), blk, 0, stream>>>(
        W1, W1T, QH, 3 * QH);
    transpose_cvt<<<dim3(QOUT / 32, QH / 32), blk, 0, stream>>>(
        Wfc, WfcT, QH, QOUT);

    const dim3 ggrid(3 * (CW >> 8), QM / 256);
    const dim3 p13grid(SEG * QB * CW / 1024);  // 4-wide threads

    for (int ci = 0; ci < nch; ++ci) {
        gemm256<0, QIN><<<ggrid, blk5, 0, stream>>>(x_bf, W0T, b0, g,
                                                    ci * CW, CW);
        scan_p1<<<p13grid, blk, 0, stream>>>(g, Aseg, Bseg, CW);
        scan_p3<<<p13grid, blk, 0, stream>>>(g, Aseg, Bseg, h0, ci * CW, CW);
    }
    for (int ci = 0; ci < nch; ++ci) {
        gemm256<0, QH><<<ggrid, blk5, 0, stream>>>(h0, W1T, b1, g,
                                                   ci * CW, CW);
        scan_p1<<<p13grid, blk, 0, stream>>>(g, Aseg, Bseg, CW);
        scan_p3<<<p13grid, blk, 0, stream>>>(g, Aseg, Bseg, h1, ci * CW, CW);
    }
    gemm256<1, QH><<<dim3(QOUT / 256, QM / 256), blk5, 0, stream>>>(
        h1, WfcT, bfc, out, 0, 0);
}

// Round 16
// 668.919 us; speedup vs baseline: 1.0096x; 1.0096x over previous
//
#include <hip/hip_runtime.h>
#include <hip/hip_bf16.h>

// QRNN: T=512, B=64, IN=512, H=1024, OUT=512. fp32 in/out.
// R14 (4th resubmit; four slots lost to GPUAcquisitionTimeout -- no data).
// 2 blocks/CU. R8-R12 pinned 121-124us across 4 schedule variants, all
// sharing ONE 512-thr workgroup/CU -> one barrier domain: when the group
// drains at lgkm(0)/s_barrier the CU idles (no pipe >40% busy; step 3025cyc
// vs ~1700 of pipe work). m114/m97 evidence: multi-block/CU overlap beats
// tighter 1-block schedules. Change: tile 128x256, 256 thr (4 waves 2Mx2N,
// per-wave 64x128, acc[4][8]), LDS 72KiB/block (3-slot BK=32 ring) -> 2
// independent blocks/CU. Same verified laneoff/XOR-swizzle/fragment pair,
// same 2-phase schedule, R11's 3-slot ledger (stage kt+2; vmcnt(6), tail 0;
// WAR slot(kt+2)=slot(kt-1) gated by end-of-step barrier). MFMA K-order
// unchanged -> bitwise-same output.
// Re-audited: LDS exact-fit (As 12288, Bs 24576 elems); swizzle row>>1&3 ==
// fl>>1&3 on both operands; vmcnt(6)=tile kt+2 in flight; WAR gated.
// Retained: XCD-chunked bijective remap, fast exp2/rcp activations,
// row-inner epilogue, 4-wide scans, p2-in-p3 batched lookback, bf16 g,
// x_bf aliased into h1, CW chunks (min 256), RNE f2bf.

#define QT 512
#define QB 64
#define QIN 512
#define QH 1024
#define QOUT 512
#define QM (QT * QB)
#define SEG 32
#define SL (QT / SEG)  // 16

typedef unsigned short ushort_t;
typedef __attribute__((ext_vector_type(8))) short bf16x8;
typedef __attribute__((ext_vector_type(4))) float f32x4;

__device__ __forceinline__ float blo(unsigned int u) {
    union { unsigned int i; float f; } v;
    v.i = u << 16;
    return v.f;
}

__device__ __forceinline__ float bhi(unsigned int u) {
    union { unsigned int i; float f; } v;
    v.i = u & 0xffff0000u;
    return v.f;
}

__device__ __forceinline__ ushort_t f2bf(float f) {
    union { float f; unsigned int i; } v;
    v.f = f;
    unsigned int r = v.i + 0x7fffu + ((v.i >> 16) & 1u);  // RNE
    return (ushort_t)(r >> 16);
}

__device__ __forceinline__ void glds16(const ushort_t* g, ushort_t* l) {
    __builtin_amdgcn_global_load_lds(
        (const __attribute__((address_space(1))) void*)g,
        (__attribute__((address_space(3))) void*)l, 16, 0, 0);
}

// --------------------------- pre-pass kernels ------------------------------
__global__ __launch_bounds__(256) void cvt_bf16(const float* __restrict__ src,
                                                ushort_t* __restrict__ dst) {
    const int i = blockIdx.x * 256 + threadIdx.x;
    float4 v = ((const float4*)src)[i];
    ushort4 o;
    o.x = f2bf(v.x); o.y = f2bf(v.y); o.z = f2bf(v.z); o.w = f2bf(v.w);
    ((ushort4*)dst)[i] = o;
}

// W (K x N fp32) -> WT (N x K bf16)
__global__ __launch_bounds__(256) void transpose_cvt(
    const float* __restrict__ W, ushort_t* __restrict__ WT, int K, int N) {
    __shared__ float t[32][33];
    const int tx = threadIdx.x & 31, ty = threadIdx.x >> 5;
    const int n0 = blockIdx.x * 32, k0 = blockIdx.y * 32;
#pragma unroll
    for (int i = 0; i < 4; ++i)
        t[ty + 8 * i][tx] = W[(size_t)(k0 + ty + 8 * i) * N + n0 + tx];
    __syncthreads();
#pragma unroll
    for (int i = 0; i < 4; ++i)
        WT[(size_t)(n0 + ty + 8 * i) * K + k0 + tx] = f2bf(t[tx][ty + 8 * i]);
}

// ------------------------------ MFMA GEMM ----------------------------------
// C = A(M x K bf16 rm) @ BT(N x K bf16 rm)^T. 256 thr = 4 waves (2M x 2N),
// tile 128x256, per-wave 64x128 (acc[4][8]). BK=32, 3-slot LDS ring (72KiB),
// 2 phases/K-step, 2 blocks/CU.
// MODE 0: bf16 g-chunk out, tanh(gate0)/sigmoid(gates1,2). MODE 1: fp32 FC.
template <int MODE, int K>
__global__ __launch_bounds__(256, 2) void gemm256(
    const ushort_t* __restrict__ A, const ushort_t* __restrict__ BT,
    const float* __restrict__ bias, void* __restrict__ out,
    int c0, int CW) {
    constexpr int NT = K / 32;
    __shared__ ushort_t As[3 * 4096];  // 3 slots x (128 rows x 32 k) = 24 KiB
    __shared__ ushort_t Bs[3 * 8192];  // 3 slots x (256 rows x 32 k) = 48 KiB

    const int tid = threadIdx.x;
    const int lane = tid & 63;
    const int w = tid >> 6;            // 0..3
    const int wr = w >> 1, wc = w & 1; // 2M x 2N

    // T1: XCD-chunked bijective remap (nwg % 8 == 0 always), M-major within.
    const int gx = gridDim.x;
    const int nwg = gx * gridDim.y;
    int flat = blockIdx.y * gx + blockIdx.x;
    flat = (flat & 7) * (nwg >> 3) + (flat >> 3);
    const int by = flat / gx;
    const int bx = flat - by * gx;
    const int m0 = by * 128;

    int nW, nOut, outstride, gate = 0;
    if (MODE == 0) {
        const int per = CW >> 8;
        gate = bx / per;
        const int nloc = (bx - gate * per) * 256;
        nW = gate * QH + c0 + nloc;
        nOut = gate * CW + nloc;
        outstride = 3 * CW;
    } else {
        nW = bx * 256;
        nOut = nW;
        outstride = QOUT;
    }

    // Staging: A 512 chunks (2/thr), B 1024 chunks (4/thr) per BK=32 tile.
    // LDS linear; global source pre-swizzled: gsrc = glds ^ ((row>>1)&3).
    size_t aoff[2];
    int ldsoA[2];
#pragma unroll
    for (int j = 0; j < 2; ++j) {
        const int c = w * 128 + j * 64 + lane;  // 0..511
        const int r = c >> 2;                   // 0..127
        const int gs = (c & 3) ^ ((r >> 1) & 3);
        aoff[j] = (size_t)(m0 + r) * K + gs * 8;
        ldsoA[j] = w * 1024 + j * 512;  // wave-uniform elems (HW adds lane*16B)
    }
    size_t boff[4];
    int ldsoB[4];
#pragma unroll
    for (int j = 0; j < 4; ++j) {
        const int c = w * 256 + j * 64 + lane;  // 0..1023
        const int r = c >> 2;                   // 0..255
        const int gs = (c & 3) ^ ((r >> 1) & 3);
        boff[j] = (size_t)(nW + r) * K + gs * 8;
        ldsoB[j] = w * 2048 + j * 512;
    }

    const int fl = lane & 15, fq = lane >> 4;
    const int laneoff = fl * 32 + ((fq ^ ((fl >> 1) & 3)) << 3);

    f32x4 acc[4][8];
#pragma unroll
    for (int i = 0; i < 4; ++i)
#pragma unroll
        for (int j = 0; j < 8; ++j) acc[i][j] = {0.f, 0.f, 0.f, 0.f};

    // Prologue: stage tiles 0,1 -> slots 0,1; wait tile0 (6 newest in flight).
#pragma unroll
    for (int t = 0; t < 2; ++t) {
#pragma unroll
        for (int j = 0; j < 2; ++j)
            glds16(A + aoff[j] + t * 32, &As[t * 4096 + ldsoA[j]]);
#pragma unroll
        for (int j = 0; j < 4; ++j)
            glds16(BT + boff[j] + t * 32, &Bs[t * 8192 + ldsoB[j]]);
    }
    asm volatile("s_waitcnt vmcnt(6)" ::: "memory");
    __builtin_amdgcn_s_barrier();

    int cur = 0, stg = 2;
    for (int kt = 0; kt < NT; ++kt) {
        const int sA = cur * 4096 + wr * 2048 + laneoff;
        const int sB = cur * 8192 + wc * 4096 + laneoff;
        const bool pf = (kt + 2 < NT);
        const size_t kb = (size_t)(kt + 2) * 32;

        bf16x8 af[4], bv[4], bw[4];
        // -------------- phase 0: j=0..3; stage A-pair of kt+2 ------------
#pragma unroll
        for (int i = 0; i < 4; ++i) af[i] = *(const bf16x8*)&As[sA + i * 512];
#pragma unroll
        for (int j = 0; j < 4; ++j) bv[j] = *(const bf16x8*)&Bs[sB + j * 512];
        if (pf) {
#pragma unroll
            for (int j = 0; j < 2; ++j)
                glds16(A + aoff[j] + kb, &As[stg * 4096 + ldsoA[j]]);
        }
        __builtin_amdgcn_sched_barrier(0);
        __builtin_amdgcn_s_barrier();
        asm volatile("s_waitcnt lgkmcnt(0)" ::: "memory");
        __builtin_amdgcn_sched_barrier(0);
        __builtin_amdgcn_s_setprio(1);
#pragma unroll
        for (int i = 0; i < 4; ++i)
#pragma unroll
            for (int j = 0; j < 4; ++j)
                acc[i][j] = __builtin_amdgcn_mfma_f32_16x16x32_bf16(
                    af[i], bv[j], acc[i][j], 0, 0, 0);
        __builtin_amdgcn_s_setprio(0);
        __builtin_amdgcn_sched_barrier(0);
        __builtin_amdgcn_s_barrier();
        // -------------- phase 1: j=4..7 (af reused); stage B of kt+2 -----
#pragma unroll
        for (int j = 0; j < 4; ++j)
            bw[j] = *(const bf16x8*)&Bs[sB + (4 + j) * 512];
        if (pf) {
#pragma unroll
            for (int j = 0; j < 4; ++j)
                glds16(BT + boff[j] + kb, &Bs[stg * 8192 + ldsoB[j]]);
        }
        __builtin_amdgcn_sched_barrier(0);
        __builtin_amdgcn_s_barrier();
        asm volatile("s_waitcnt lgkmcnt(0)" ::: "memory");
        __builtin_amdgcn_sched_barrier(0);
        __builtin_amdgcn_s_setprio(1);
#pragma unroll
        for (int i = 0; i < 4; ++i)
#pragma unroll
            for (int j = 0; j < 4; ++j)
                acc[i][4 + j] = __builtin_amdgcn_mfma_f32_16x16x32_bf16(
                    af[i], bw[j], acc[i][4 + j], 0, 0, 0);
        __builtin_amdgcn_s_setprio(0);
        // End-of-step: tile kt+1 retired; in-flight = tile kt+2 (6 loads).
        if (kt < NT - 2)
            asm volatile("s_waitcnt vmcnt(6)" ::: "memory");
        else if (kt == NT - 2)
            asm volatile("s_waitcnt vmcnt(0)" ::: "memory");
        __builtin_amdgcn_sched_barrier(0);
        if (kt < NT - 1) __builtin_amdgcn_s_barrier();
        cur = (cur == 2) ? 0 : cur + 1;
        stg = (stg == 2) ? 0 : stg + 1;
    }

    // Fast activation constants (wave-uniform): v = a*rcp(1+exp2(k*v)) + d.
    const float ak = (gate == 0) ? 2.8853900817779268f : -1.4426950408889634f;
    const float aa = (gate == 0) ? -2.f : 1.f;
    const float ad = (gate == 0) ? 1.f : 0.f;

    // Epilogue. C/D: col = lane&15, row = (lane>>4)*4 + reg. Row-inner j-loop
    // so the sector-stores of each output line issue back-to-back.
    float bvv[8];
#pragma unroll
    for (int j = 0; j < 8; ++j) bvv[j] = bias[nW + wc * 128 + j * 16 + fl];
#pragma unroll
    for (int i = 0; i < 4; ++i) {
#pragma unroll
        for (int r = 0; r < 4; ++r) {
            const int row = m0 + wr * 64 + i * 16 + fq * 4 + r;
#pragma unroll
            for (int j = 0; j < 8; ++j) {
                const int col = nOut + wc * 128 + j * 16 + fl;
                float v = acc[i][j][r] + bvv[j];
                if (MODE == 0) {
                    v = aa * __builtin_amdgcn_rcpf(
                                 1.f + __builtin_amdgcn_exp2f(ak * v)) +
                        ad;
                    ((ushort_t*)out)[(size_t)row * outstride + col] = f2bf(v);
                } else {
                    ((float*)out)[(size_t)row * outstride + col] = v;
                }
            }
        }
    }
}

// ----------------------- segmented fo-scan (2 passes) ----------------------
// g: (T, B, 3, CW) bf16 activated z,f,o. c = f*c + (1-f)*z as (A,B) pairs.
// 4-wide: each thread owns 4 consecutive hh.

// Pass 1: per-(seg,b,hh4) summary. idx4 covers hh = 4*(idx4 % (CW/4)).
__global__ __launch_bounds__(256) void scan_p1(const ushort_t* __restrict__ g,
                                               float* __restrict__ Aseg,
                                               float* __restrict__ Bseg,
                                               int CW) {
    const int idx4 = blockIdx.x * 256 + threadIdx.x;
    const int cw4 = CW >> 2;
    const int hh = (idx4 % cw4) << 2;
    const int sb = idx4 / cw4;
    const int b = sb % QB;
    const int s = sb / QB;
    const ushort_t* gp = g + ((size_t)(s * SL * QB + b) * 3) * CW + hh;
    const size_t grow = (size_t)QB * 3 * CW;
    uint2 zu[SL], fu[SL];
#pragma unroll
    for (int t = 0; t < SL; ++t) {
        zu[t] = *(const uint2*)gp;
        fu[t] = *(const uint2*)(gp + CW);
        gp += grow;
    }
    float4 A = {1.f, 1.f, 1.f, 1.f}, Bc = {0.f, 0.f, 0.f, 0.f};
#pragma unroll
    for (int t = 0; t < SL; ++t) {
        const float f0 = blo(fu[t].x), f1 = bhi(fu[t].x);
        const float f2 = blo(fu[t].y), f3 = bhi(fu[t].y);
        Bc.x = f0 * Bc.x + (1.f - f0) * blo(zu[t].x);
        Bc.y = f1 * Bc.y + (1.f - f1) * bhi(zu[t].x);
        Bc.z = f2 * Bc.z + (1.f - f2) * blo(zu[t].y);
        Bc.w = f3 * Bc.w + (1.f - f3) * bhi(zu[t].y);
        A.x *= f0; A.y *= f1; A.z *= f2; A.w *= f3;
    }
    const size_t oidx = (size_t)sb * CW + hh;
    *(float4*)&Aseg[oidx] = A;
    *(float4*)&Bseg[oidx] = Bc;
}

// Pass 2 (p2+p3 fused): inline-scan preceding segment summaries for cstart
// (batched 8-wide lookback; fold order unchanged -> bitwise identical), then
// recompute interior states, write h (bf16, 4-wide).
__global__ __launch_bounds__(256) void scan_p3(const ushort_t* __restrict__ g,
                                               const float* __restrict__ Aseg,
                                               const float* __restrict__ Bseg,
                                               ushort_t* __restrict__ h,
                                               int c0, int CW) {
    const int idx4 = blockIdx.x * 256 + threadIdx.x;
    const int cw4 = CW >> 2;
    const int hh = (idx4 % cw4) << 2;
    const int sb = idx4 / cw4;
    const int b = sb % QB;
    const int s = sb / QB;
    const ushort_t* gp = g + ((size_t)(s * SL * QB + b) * 3) * CW + hh;
    ushort_t* hp = h + (size_t)(s * SL * QB + b) * QH + c0 + hh;
    const size_t grow = (size_t)QB * 3 * CW;
    const size_t hrow = (size_t)QB * QH;
    uint2 zu[SL], fu[SL], ou[SL];
#pragma unroll
    for (int t = 0; t < SL; ++t) {
        zu[t] = *(const uint2*)gp;
        fu[t] = *(const uint2*)(gp + CW);
        ou[t] = *(const uint2*)(gp + 2 * CW);
        gp += grow;
    }
    // Inline p2: c = fold over segments s' < s, batched 8 at a time.
    float4 c = {0.f, 0.f, 0.f, 0.f};
    const size_t stride = (size_t)QB * CW;
    const size_t colo = (size_t)b * CW + hh;
    int sp = 0;
    while (sp + 8 <= s) {
        float4 Av[8], Bv[8];
#pragma unroll
        for (int q = 0; q < 8; ++q) {
            const size_t o = (size_t)(sp + q) * stride + colo;
            Av[q] = *(const float4*)&Aseg[o];
            Bv[q] = *(const float4*)&Bseg[o];
        }
#pragma unroll
        for (int q = 0; q < 8; ++q) {
            c.x = Av[q].x * c.x + Bv[q].x;
            c.y = Av[q].y * c.y + Bv[q].y;
            c.z = Av[q].z * c.z + Bv[q].z;
            c.w = Av[q].w * c.w + Bv[q].w;
        }
        sp += 8;
    }
    if (sp < s) {
        float4 Av[8], Bv[8];
#pragma unroll
        for (int q = 0; q < 8; ++q) {
            const int si = (sp + q < SEG) ? sp + q : SEG - 1;  // clamp, in-bounds
            const size_t o = (size_t)si * stride + colo;
            Av[q] = *(const float4*)&Aseg[o];
            Bv[q] = *(const float4*)&Bseg[o];
        }
#pragma unroll
        for (int q = 0; q < 8; ++q) {
            if (sp + q < s) {
                c.x = Av[q].x * c.x + Bv[q].x;
                c.y = Av[q].y * c.y + Bv[q].y;
                c.z = Av[q].z * c.z + Bv[q].z;
                c.w = Av[q].w * c.w + Bv[q].w;
            }
        }
    }
#pragma unroll
    for (int t = 0; t < SL; ++t) {
        const float f0 = blo(fu[t].x), f1 = bhi(fu[t].x);
        const float f2 = blo(fu[t].y), f3 = bhi(fu[t].y);
        c.x = f0 * c.x + (1.f - f0) * blo(zu[t].x);
        c.y = f1 * c.y + (1.f - f1) * bhi(zu[t].x);
        c.z = f2 * c.z + (1.f - f2) * blo(zu[t].y);
        c.w = f3 * c.w + (1.f - f3) * bhi(zu[t].y);
        ushort4 hv;
        hv.x = f2bf(blo(ou[t].x) * c.x);
        hv.y = f2bf(bhi(ou[t].x) * c.y);
        hv.z = f2bf(blo(ou[t].y) * c.z);
        hv.w = f2bf(bhi(ou[t].y) * c.w);
        *(ushort4*)hp = hv;
        hp += hrow;
    }
}

extern "C" void kernel_launch(void* const* d_in, const int* in_sizes, int n_in,
                              void* d_out, int out_size, void* d_ws,
                              size_t ws_size, hipStream_t stream) {
    const float* x   = (const float*)d_in[0];
    const float* W0  = (const float*)d_in[1];
    const float* b0  = (const float*)d_in[2];
    const float* W1  = (const float*)d_in[3];
    const float* b1  = (const float*)d_in[4];
    const float* Wfc = (const float*)d_in[5];
    const float* bfc = (const float*)d_in[6];
    float* out = (float*)d_out;

    char* p = (char*)d_ws;
    ushort_t* h0   = (ushort_t*)p;  p += (size_t)QM * QH * 2;
    ushort_t* h1   = (ushort_t*)p;  // x_bf aliases h1 (dead before h1 write)
    ushort_t* x_bf = (ushort_t*)p;  p += (size_t)QM * QH * 2;
    ushort_t* W0T  = (ushort_t*)p;  p += (size_t)3 * QH * QIN * 2;
    ushort_t* W1T  = (ushort_t*)p;  p += (size_t)3 * QH * QH * 2;
    ushort_t* WfcT = (ushort_t*)p;  p += (size_t)QOUT * QH * 2;
    const size_t base = (size_t)(p - (char*)d_ws);

    // Largest CW (>=256) fitting ws (Aseg+Bseg+g budget).
    int CW = QH;
    while (CW > 256 &&
           base + 2 * (size_t)QB * CW * SEG * 4 + (size_t)QM * 3 * CW * 2 >
               ws_size)
        CW >>= 1;
    const int nch = QH / CW;

    float* Aseg   = (float*)p;  p += (size_t)QB * CW * SEG * 4;
    float* Bseg   = (float*)p;  p += (size_t)QB * CW * SEG * 4;
    ushort_t* g   = (ushort_t*)p;

    dim3 blk(256);

    cvt_bf16<<<dim3(QM * QIN / 1024), blk, 0, stream>>>(x, x_bf);
    transpose_cvt<<<dim3(3 * QH / 32, QIN / 32), blk, 0, stream>>>(
        W0, W0T, QIN, 3 * QH);
    transpose_cvt<<<dim3(3 * QH / 32, QH / 32), blk, 0, stream>>>(
        W1, W1T, QH, 3 * QH);
    transpose_cvt<<<dim3(QOUT / 32, QH / 32), blk, 0, stream>>>(
        Wfc, WfcT, QH, QOUT);

    const dim3 ggrid(3 * (CW >> 8), QM / 128);
    const dim3 p13grid(SEG * QB * CW / 1024);  // 4-wide threads

    for (int ci = 0; ci < nch; ++ci) {
        gemm256<0, QIN><<<ggrid, blk, 0, stream>>>(x_bf, W0T, b0, g,
                                                   ci * CW, CW);
        scan_p1<<<p13grid, blk, 0, stream>>>(g, Aseg, Bseg, CW);
        scan_p3<<<p13grid, blk, 0, stream>>>(g, Aseg, Bseg, h0, ci * CW, CW);
    }
    for (int ci = 0; ci < nch; ++ci) {
        gemm256<0, QH><<<ggrid, blk, 0, stream>>>(h0, W1T, b1, g,
                                                  ci * CW, CW);
        scan_p1<<<p13grid, blk, 0, stream>>>(g, Aseg, Bseg, CW);
        scan_p3<<<p13grid, blk, 0, stream>>>(g, Aseg, Bseg, h1, ci * CW, CW);
    }
    gemm256<1, QH><<<dim3(QOUT / 256, QM / 128), blk, 0, stream>>>(
        h1, WfcT, bfc, out, 0, 0);
}